// Round 4
// baseline (350.671 us; speedup 1.0000x reference)
//
#include <hip/hip_runtime.h>
#include <stdint.h>

typedef __attribute__((ext_vector_type(4))) int   i32x4v;
typedef __attribute__((ext_vector_type(16))) int  i32x16v;
typedef __attribute__((ext_vector_type(4))) float f32x4;

#define NBATCH 32
#define HP 58
#define WP 58
#define PIX 3136            // 56*56
#define WW 56

// workspace layout (bytes), all i8
#define XBP_BYTES ((size_t)NBATCH*HP*WP*256)      // 27,557,888 per tensor
#define OFF_XBP2  (XBP_BYTES)
#define OFF_WBT   (2*XBP_BYTES)
#define WBT_BYTES ((size_t)9*256*256)             // 589,824
#define OFF_FLAG  (OFF_WBT + WBT_BYTES)
#define WS_NEED   (OFF_FLAG + 64)

__global__ void k_zero(uint4* p, int n16) {
    int i = blockIdx.x * blockDim.x + threadIdx.x;
    int stride = gridDim.x * blockDim.x;
    uint4 z = {0u, 0u, 0u, 0u};
    for (; i < n16; i += stride) p[i] = z;
}

// wbT[kk][oc][c] = sign(weight[oc][c][kk]) as i8
__global__ void k_repack_w(const float* __restrict__ w, char* __restrict__ wbT) {
    int idx = blockIdx.x * 256 + threadIdx.x;     // 0 .. 589823
    int c  = idx & 255;
    int oc = (idx >> 8) & 255;
    int kk = idx >> 16;
    float v = w[(oc * 256 + c) * 9 + kk];
    wbT[idx] = (v > 0.f) ? (char)1 : ((v < 0.f) ? (char)-1 : (char)0);
}

__global__ void k_flag(const float* __restrict__ s1, const float* __restrict__ s2,
                       int* __restrict__ flag) {
    __shared__ int bad;
    int t = threadIdx.x;
    if (t == 0) bad = 0;
    __syncthreads();
    if (s1[t] != s2[t]) atomicAdd(&bad, 1);
    __syncthreads();
    if (t == 0) *flag = (bad == 0) ? 1 : 0;
}

// NCHW fp32 -> halo-padded NHWC i8: xbp[n][y+1][x+1][c] = sign(x + shift)
__global__ __launch_bounds__(256) void k_repack_x(
    const float* __restrict__ x, const float* __restrict__ sh1,
    const float* __restrict__ sh2, char* __restrict__ xbp1,
    char* __restrict__ xbp2, const int* __restrict__ flag) {
    __shared__ float lds[64 * 68];
    bool eq = (*flag != 0);
    int t = threadIdx.x;
    int b = blockIdx.x;
    int n = b / 49;
    int p0 = (b % 49) * 64;

    // write-phase mapping: 4 threads per pixel, 16 channels (16 B) each
    int pixw = t >> 2;
    int c16  = (t & 3) * 16;
    int pw = p0 + pixw;
    int yw = pw / WW, xw = pw % WW;
    size_t obase = ((size_t)(n * HP + yw + 1) * WP + (xw + 1)) * 256;

    // load-phase mapping
    int cl = t >> 4;
    int p4 = (t & 15) * 4;

    for (int cc = 0; cc < 256; cc += 64) {
        __syncthreads();
#pragma unroll
        for (int i = 0; i < 4; ++i) {
            float4 v = *(const float4*)(x + (size_t)(n * 256 + cc + cl + i * 16) * PIX + p0 + p4);
            *(float4*)(&lds[(cl + i * 16) * 68 + p4]) = v;
        }
        __syncthreads();
        union { char c[16]; int4 v; } u1, u2;
#pragma unroll
        for (int k = 0; k < 16; ++k) {
            int c = c16 + k;
            float v = lds[c * 68 + pixw];
            float a1 = v + sh1[cc + c];
            float a2 = v + sh2[cc + c];
            u1.c[k] = (a1 > 0.f) ? (char)1 : ((a1 < 0.f) ? (char)-1 : (char)0);
            u2.c[k] = (a2 > 0.f) ? (char)1 : ((a2 < 0.f) ? (char)-1 : (char)0);
        }
        *(int4*)(xbp1 + obase + cc + c16) = u1.v;
        if (!eq) *(int4*)(xbp2 + obase + cc + c16) = u2.v;
    }
}

// Implicit-GEMM binary conv, int8 MFMA. REG-STAGED (no global_load_lds this round).
// Block: 256 threads = 4 waves (2x2). Tile: 128 pixels x 128 oc. BK=64 channels.
// LDS image: LDS[row][ch] = tile[row][ch ^ ((row>>1)&3)]  (source pre-swizzle,
// linear lane*16 write), undone identically on the read side.
template <bool EQ>
__global__ __launch_bounds__(256) void k_bgemm(
    const char* __restrict__ xbp1, const char* __restrict__ xbp2,
    const char* __restrict__ wbT, const float* __restrict__ bias,
    const float* __restrict__ w1, const int* __restrict__ flag,
    float* __restrict__ out) {
    if ((*flag != 0) != EQ) return;   // block-uniform; exactly one instantiation runs

    constexpr int LDSB = EQ ? 16384 : 24576;
    __shared__ int4 lds4[LDSB / 16];
    char* lds = (char*)lds4;
    const char* As1 = lds;
    const char* Bsm = lds + 8192;
    const char* As2 = lds + 16384;    // !EQ only

    int t = threadIdx.x;
    int l = t & 63, wid = t >> 6;
    int mtile = blockIdx.x >> 1, ntile = blockIdx.x & 1;
    int wr = wid >> 1, wc = wid & 1;
    int r32 = l & 31, half = l >> 5;

    // ---- staging slot setup: 16 (EQ) / 24 (!EQ) slots of 1KB, SPW per wave ----
    constexpr int SPW = EQ ? 4 : 6;
    const char* gptr[SPW];
    int ldsoff[SPW];                  // linear dest: ldsoff[j] + l*16
    int isB[SPW];
#pragma unroll
    for (int j = 0; j < SPW; ++j) {
        int s = wid * SPW + j;
        int rl = l >> 2;              // row within 16-row slot
        int ch = l & 3;               // 16B chunk within 64B row
        int region;                   // 0=A1, 1=A2, 2=B
        if constexpr (EQ) region = (s < 8) ? 0 : 2;
        else              region = (s < 8) ? 0 : ((s < 16) ? 1 : 2);
        int blk = s & 7;
        int row = blk * 16 + rl;
        int sc = ch ^ ((row >> 1) & 3);   // source-side swizzle
        if (region == 2) {
            gptr[j] = wbT + (size_t)(ntile * 128 + row) * 256 + sc * 16;
            ldsoff[j] = 8192 + blk * 1024;
        } else {
            int gp = mtile * 128 + row;
            int n = gp / PIX, p = gp - n * PIX;
            int y = p / WW, xx = p - y * WW;
            const char* src = (region == 1) ? xbp2 : xbp1;
            gptr[j] = src + ((size_t)(n * HP + y + 1) * WP + (xx + 1)) * 256 + sc * 16;
            ldsoff[j] = (region == 1 ? 16384 : 0) + blk * 1024;
        }
        isB[j] = (region == 2) ? 1 : 0;
    }

    i32x16v acc[2][2], acc2[2][2];
#pragma unroll
    for (int mi = 0; mi < 2; ++mi)
#pragma unroll
        for (int ni = 0; ni < 2; ++ni)
#pragma unroll
            for (int i = 0; i < 16; ++i) {
                acc[mi][ni][i] = 0;
                if constexpr (!EQ) acc2[mi][ni][i] = 0;
            }

    for (int kk = 0; kk < 9; ++kk) {
        int kdisp = ((kk / 3 - 1) * WP + (kk % 3 - 1)) * 256;
        int bd0 = kk * 65536;
        for (int cc = 0; cc < 256; cc += 64) {
            int da = kdisp + cc;
            int db = bd0 + cc;
            int4 v[SPW];
#pragma unroll
            for (int j = 0; j < SPW; ++j)
                v[j] = *(const int4*)(gptr[j] + (isB[j] ? db : da));
            __syncthreads();           // previous step's frag reads retired
#pragma unroll
            for (int j = 0; j < SPW; ++j)
                *(int4*)(lds + ldsoff[j] + l * 16) = v[j];
            __syncthreads();           // tiles ready

            i32x4v af[2][2], bf[2][2], af2[2][2];
#pragma unroll
            for (int mi = 0; mi < 2; ++mi)
#pragma unroll
                for (int kq = 0; kq < 2; ++kq) {
                    int ar = wr * 64 + mi * 32 + r32;
                    int ci = (kq * 2 + half) ^ ((ar >> 1) & 3);
                    af[mi][kq] = *(const i32x4v*)(As1 + ar * 64 + ci * 16);
                    if constexpr (!EQ)
                        af2[mi][kq] = *(const i32x4v*)(As2 + ar * 64 + ci * 16);
                }
#pragma unroll
            for (int ni = 0; ni < 2; ++ni)
#pragma unroll
                for (int kq = 0; kq < 2; ++kq) {
                    int br = wc * 64 + ni * 32 + r32;
                    int ci = (kq * 2 + half) ^ ((br >> 1) & 3);
                    bf[ni][kq] = *(const i32x4v*)(Bsm + br * 64 + ci * 16);
                }
#pragma unroll
            for (int kq = 0; kq < 2; ++kq)
#pragma unroll
                for (int mi = 0; mi < 2; ++mi)
#pragma unroll
                    for (int ni = 0; ni < 2; ++ni) {
                        acc[mi][ni] = __builtin_amdgcn_mfma_i32_32x32x32_i8(
                            af[mi][kq], bf[ni][kq], acc[mi][ni], 0, 0, 0);
                        if constexpr (!EQ)
                            acc2[mi][ni] = __builtin_amdgcn_mfma_i32_32x32x32_i8(
                                af2[mi][kq], bf[ni][kq], acc2[mi][ni], 0, 0, 0);
                    }
        }
    }

    // epilogue: D 32x32 layout: col(oc) = lane&31, row(pixel) = (reg&3)+8*(reg>>2)+4*(lane>>5)
    float w1v = w1[0];
    float se = 1.f + w1v;
#pragma unroll
    for (int mi = 0; mi < 2; ++mi)
#pragma unroll
        for (int ni = 0; ni < 2; ++ni) {
            int oc = ntile * 128 + wc * 64 + ni * 32 + r32;
            float bv = bias[oc];
#pragma unroll
            for (int q = 0; q < 4; ++q) {
                int gp = mtile * 128 + wr * 64 + mi * 32 + q * 8 + half * 4;
                int n = gp / PIX, p = gp - n * PIX;
                f32x4 r;
                if constexpr (EQ) {
#pragma unroll
                    for (int j2 = 0; j2 < 4; ++j2)
                        r[j2] = ((float)acc[mi][ni][q * 4 + j2] + bv) * se;
                } else {
#pragma unroll
                    for (int j2 = 0; j2 < 4; ++j2)
                        r[j2] = (float)acc[mi][ni][q * 4 + j2]
                              + w1v * (float)acc2[mi][ni][q * 4 + j2] + se * bv;
                }
                *(f32x4*)(out + ((size_t)n * 256 + oc) * PIX + p) = r;
            }
        }
}

extern "C" void kernel_launch(void* const* d_in, const int* in_sizes, int n_in,
                              void* d_out, int out_size, void* d_ws, size_t ws_size,
                              hipStream_t stream) {
    const float* x    = (const float*)d_in[0];
    const float* sh1  = (const float*)d_in[1];
    const float* sh2  = (const float*)d_in[2];
    const float* wgt  = (const float*)d_in[3];
    const float* bias = (const float*)d_in[4];
    const float* w1   = (const float*)d_in[5];
    float* out = (float*)d_out;
    char* ws = (char*)d_ws;
    if (ws_size < WS_NEED) return;

    char* xbp1 = ws;
    char* xbp2 = ws + OFF_XBP2;
    char* wbT  = ws + OFF_WBT;
    int* flag  = (int*)(ws + OFF_FLAG);

    k_zero<<<2048, 256, 0, stream>>>((uint4*)ws, (int)(2 * XBP_BYTES / 16));
    k_repack_w<<<2304, 256, 0, stream>>>(wgt, wbT);
    k_flag<<<1, 256, 0, stream>>>(sh1, sh2, flag);
    k_repack_x<<<32 * 49, 256, 0, stream>>>(x, sh1, sh2, xbp1, xbp2, flag);
    k_bgemm<true><<<1568, 256, 0, stream>>>(xbp1, xbp2, wbT, bias, w1, flag, out);
    k_bgemm<false><<<1568, 256, 0, stream>>>(xbp1, xbp2, wbT, bias, w1, flag, out);
}

// Round 5
// 167.736 us; speedup vs baseline: 2.0906x; 2.0906x over previous
//
#include <hip/hip_runtime.h>
#include <stdint.h>

typedef __attribute__((ext_vector_type(4))) int   i32x4v;
typedef __attribute__((ext_vector_type(16))) int  i32x16v;
typedef __attribute__((ext_vector_type(4))) float f32x4;

#define PIX 3136            // 56*56
#define WW 56
#define SLAB 215296         // 58*58*64 bytes, one (n,chunk) plane
#define APLANE 5600         // LDS bytes per 16B-subchunk plane (350 units, 350%8=6 -> conflict-free)
#define AWIN   22400        // 4 * APLANE
#define BSTG   16384        // one B buffer: 4 sub * 256 oc * 16B
#define LDSB   (AWIN + 2*BSTG)   // 55168

// workspace (bytes): two planar i8 tensors + transposed weights + flag
#define XBP_BYTES ((size_t)32*4*3364*64)          // 27,557,888
#define OFF_XBP2  (XBP_BYTES)
#define OFF_WBT   (2*XBP_BYTES)
#define WBT_BYTES ((size_t)9*16*256*16)           // 589,824
#define OFF_FLAG  (OFF_WBT + WBT_BYTES)
#define WS_NEED   (OFF_FLAG + 64)

__global__ void k_zero(uint4* p, int n16) {
    int i = blockIdx.x * blockDim.x + threadIdx.x;
    int stride = gridDim.x * blockDim.x;
    uint4 z = {0u, 0u, 0u, 0u};
    for (; i < n16; i += stride) p[i] = z;
}

// wbTt[kk][sub16][oc256][16B]: byte idx -> c = sub*16+lo
__global__ void k_repack_w(const float* __restrict__ w, char* __restrict__ wbTt) {
    int idx = blockIdx.x * 256 + threadIdx.x;     // 0..589823
    int kk = idx >> 16;
    int sub = (idx >> 12) & 15;
    int oc = (idx >> 4) & 255;
    int lo = idx & 15;
    int c = sub * 16 + lo;
    float v = w[(oc * 256 + c) * 9 + kk];
    wbTt[idx] = (v > 0.f) ? (char)1 : ((v < 0.f) ? (char)-1 : (char)0);
}

__global__ void k_flag(const float* __restrict__ s1, const float* __restrict__ s2,
                       int* __restrict__ flag) {
    __shared__ int bad;
    int t = threadIdx.x;
    if (t == 0) bad = 0;
    __syncthreads();
    if (s1[t] != s2[t]) atomicAdd(&bad, 1);
    __syncthreads();
    if (t == 0) *flag = (bad == 0) ? 1 : 0;
}

// NCHW fp32 -> planar halo-padded i8: xbp[n][plane4][py][px][64] = sign(x+shift)
__global__ __launch_bounds__(256) void k_repack_x(
    const float* __restrict__ x, const float* __restrict__ sh1,
    const float* __restrict__ sh2, char* __restrict__ xbp1,
    char* __restrict__ xbp2, const int* __restrict__ flag) {
    __shared__ float lds[64 * 68];
    bool eq = (*flag != 0);
    int t = threadIdx.x;
    int b = blockIdx.x;
    int n = b / 49;
    int p0 = (b % 49) * 64;

    int pixw = t >> 2;               // 0..63
    int sub  = t & 3;                // 16B subchunk within 64-ch plane
    int pw = p0 + pixw;
    int yw = pw / WW, xw = pw % WW;

    int cl = t >> 4;
    int p4 = (t & 15) * 4;

    for (int cc = 0; cc < 256; cc += 64) {
        __syncthreads();
#pragma unroll
        for (int i = 0; i < 4; ++i) {
            float4 v = *(const float4*)(x + (size_t)(n * 256 + cc + cl + i * 16) * PIX + p0 + p4);
            *(float4*)(&lds[(cl + i * 16) * 68 + p4]) = v;
        }
        __syncthreads();
        size_t obase = (size_t)(n * 4 + (cc >> 6)) * SLAB
                     + ((size_t)(yw + 1) * 58 + (xw + 1)) * 64 + sub * 16;
        union { char c[16]; int4 v; } u1, u2;
#pragma unroll
        for (int k = 0; k < 16; ++k) {
            int c = sub * 16 + k;
            float v = lds[c * 68 + pixw];
            float a1 = v + sh1[cc + c];
            float a2 = v + sh2[cc + c];
            u1.c[k] = (a1 > 0.f) ? (char)1 : ((a1 < 0.f) ? (char)-1 : (char)0);
            u2.c[k] = (a2 > 0.f) ? (char)1 : ((a2 < 0.f) ? (char)-1 : (char)0);
        }
        *(int4*)(xbp1 + obase) = u1.v;
        if (!eq) *(int4*)(xbp2 + obase) = u2.v;
    }
}

// Implicit-GEMM binary conv, i8 MFMA, A-window reuse across 9 taps.
// Block: 256 thr = 4 waves (2x2). Tile 128px x 256oc. Wave tile 64x128.
// MODE 0: EQ final: out=(acc+b)*(1+w1). MODE 1: out=acc+(1+w1)b. MODE 2: out+=w1*acc.
template <int MODE>
__global__ __launch_bounds__(256, 2) void k_bgemm(
    const char* __restrict__ xsrc, const char* __restrict__ wbTt,
    const float* __restrict__ bias, const float* __restrict__ w1,
    const int* __restrict__ flag, float* __restrict__ out) {
    bool eq = (*flag != 0);
    if (MODE == 0 ? !eq : eq) return;    // block-uniform

    __shared__ int4 lds16[LDSB / 16];
    char* lds = (char*)lds16;

    int t = threadIdx.x;
    int l = t & 63, wid = t >> 6;
    int wr = wid >> 1, wc = wid & 1;
    int r32 = l & 31, half = l >> 5;
    int b = blockIdx.x;
    int n = b / 25, tp = b % 25;
    int p0 = tp * 128;
    int y0 = p0 / WW;
    int pyw0 = (y0 < 52) ? y0 : 52;      // 6-row window rows pyw0..pyw0+5

    // per-lane window pixel index for its two 32-px row groups
    int wpm[2];
#pragma unroll
    for (int mi = 0; mi < 2; ++mi) {
        int g = p0 + wr * 64 + mi * 32 + r32;   // < 3200 (pad tail reads halo rows)
        int y = g / WW, xx = g - y * WW;
        wpm[mi] = (y + 1 - pyw0) * 58 + xx + 1;
    }

    // prologue prefetch: A window (cc=0) and B (s=0)
    int4 rA[6], rB[4];
    {
        const char* sb = xsrc + (size_t)(n * 4) * SLAB + (size_t)pyw0 * 3712;
#pragma unroll
        for (int j = 0; j < 6; ++j) {
            int u = t + j * 256;
            if (u < 1392) rA[j] = *(const int4*)(sb + u * 16);
        }
#pragma unroll
        for (int j = 0; j < 4; ++j)
            rB[j] = *(const int4*)(wbTt + (t + j * 256) * 16);
    }

    i32x16v acc[2][2][2];    // [mi][nj-pair? no: mi][ni-half] -> use [mi][ni] with ni 0..3 split below
    // acc[mi][nh][?]: flatten ni 0..3 as [nh][np]: keep 2x4 via two dims
    // (statically indexed everywhere)
    i32x16v a0[2], a1[2], a2[2], a3[2];  // a<ni>[mi]
#pragma unroll
    for (int mi = 0; mi < 2; ++mi) {
        for (int i = 0; i < 16; ++i) { a0[mi][i]=0; a1[mi][i]=0; a2[mi][i]=0; a3[mi][i]=0; }
    }
    (void)acc;

    for (int cc = 0; cc < 4; ++cc) {
        __syncthreads();                 // all taps of prev cc done -> Awin reusable
#pragma unroll
        for (int j = 0; j < 6; ++j) {
            int u = t + j * 256;
            if (u < 1392)
                *(int4*)(lds + (u & 3) * APLANE + (u >> 2) * 16) = rA[j];
        }
        if (cc < 3) {
            const char* sb = xsrc + (size_t)(n * 4 + cc + 1) * SLAB + (size_t)pyw0 * 3712;
#pragma unroll
            for (int j = 0; j < 6; ++j) {
                int u = t + j * 256;
                if (u < 1392) rA[j] = *(const int4*)(sb + u * 16);
            }
        }
#pragma unroll
        for (int kk = 0; kk < 9; ++kk) {
            int bOff = AWIN + ((cc * 9 + kk) & 1) * BSTG;
#pragma unroll
            for (int j = 0; j < 4; ++j)
                *(int4*)(lds + bOff + (t + j * 256) * 16) = rB[j];
            asm volatile("s_waitcnt lgkmcnt(0)\ns_barrier" ::: "memory");
            // issue next B stage
            {
                int kn = (kk == 8) ? 0 : (kk + 1);
                int cn = (kk == 8) ? (cc + 1) : cc;
                if (cn < 4) {
                    const char* gb = wbTt + ((kn * 16 + cn * 4) << 12);
#pragma unroll
                    for (int j = 0; j < 4; ++j)
                        rB[j] = *(const int4*)(gb + (t + j * 256) * 16);
                }
            }
            const int ts = (kk / 3 - 1) * 58 + (kk % 3) - 1;
#pragma unroll
            for (int kq = 0; kq < 2; ++kq) {
                int ci = kq * 2 + half;
                i32x4v af[2], bf[4];
#pragma unroll
                for (int mi = 0; mi < 2; ++mi)
                    af[mi] = *(const i32x4v*)(lds + ci * APLANE + (wpm[mi] + ts) * 16);
#pragma unroll
                for (int ni = 0; ni < 4; ++ni)
                    bf[ni] = *(const i32x4v*)(lds + bOff + ci * 4096
                                              + (wc * 128 + ni * 32 + r32) * 16);
#pragma unroll
                for (int mi = 0; mi < 2; ++mi) {
                    a0[mi] = __builtin_amdgcn_mfma_i32_32x32x32_i8(af[mi], bf[0], a0[mi], 0, 0, 0);
                    a1[mi] = __builtin_amdgcn_mfma_i32_32x32x32_i8(af[mi], bf[1], a1[mi], 0, 0, 0);
                    a2[mi] = __builtin_amdgcn_mfma_i32_32x32x32_i8(af[mi], bf[2], a2[mi], 0, 0, 0);
                    a3[mi] = __builtin_amdgcn_mfma_i32_32x32x32_i8(af[mi], bf[3], a3[mi], 0, 0, 0);
                }
            }
        }
    }

    // ---- epilogue: LDS transpose per wave -> coalesced 256B-row stores ----
    __syncthreads();
    float w1v = w1[0];
    float se = 1.f + w1v;
    int pbase = p0 + wr * 64;
    bool pvalid = pbase < PIX;
    char* wb = lds + wid * 8704;         // 32 rows x 272B

#pragma unroll
    for (int ni = 0; ni < 4; ++ni) {
        int oc = wc * 128 + ni * 32 + r32;
        float bv = bias[oc];
        asm volatile("s_waitcnt lgkmcnt(0)" ::: "memory");
#pragma unroll
        for (int mi = 0; mi < 2; ++mi) {
            const i32x16v* ap = (ni == 0) ? &a0[mi] : (ni == 1) ? &a1[mi]
                              : (ni == 2) ? &a2[mi] : &a3[mi];
#pragma unroll
            for (int q = 0; q < 4; ++q) {
                f32x4 v;
#pragma unroll
                for (int j = 0; j < 4; ++j) {
                    float a = (float)((*ap)[q * 4 + j]);
                    if (MODE == 0)      v[j] = (a + bv) * se;
                    else if (MODE == 1) v[j] = a + se * bv;
                    else                v[j] = w1v * a;
                }
                *(f32x4*)(wb + r32 * 272 + (mi * 32 + q * 8 + half * 4) * 4) = v;
            }
        }
        asm volatile("s_waitcnt lgkmcnt(0)" ::: "memory");
        if (pvalid) {
#pragma unroll
            for (int pr = 0; pr < 8; ++pr) {
                int ocr = pr * 4 + (l >> 4);
                int px16 = l & 15;
                f32x4 v = *(const f32x4*)(wb + ocr * 272 + px16 * 16);
                float* op = out + ((size_t)n * 256 + wc * 128 + ni * 32 + ocr) * PIX
                          + pbase + px16 * 4;
                if (MODE == 2) {
                    f32x4 o = *(const f32x4*)op;
                    v[0] += o[0]; v[1] += o[1]; v[2] += o[2]; v[3] += o[3];
                }
                *(f32x4*)op = v;
            }
        }
    }
}

extern "C" void kernel_launch(void* const* d_in, const int* in_sizes, int n_in,
                              void* d_out, int out_size, void* d_ws, size_t ws_size,
                              hipStream_t stream) {
    const float* x    = (const float*)d_in[0];
    const float* sh1  = (const float*)d_in[1];
    const float* sh2  = (const float*)d_in[2];
    const float* wgt  = (const float*)d_in[3];
    const float* bias = (const float*)d_in[4];
    const float* w1   = (const float*)d_in[5];
    float* out = (float*)d_out;
    char* ws = (char*)d_ws;
    if (ws_size < WS_NEED) return;

    char* xbp1 = ws;
    char* xbp2 = ws + OFF_XBP2;
    char* wbTt = ws + OFF_WBT;
    int* flag  = (int*)(ws + OFF_FLAG);

    k_zero<<<2048, 256, 0, stream>>>((uint4*)ws, (int)(2 * XBP_BYTES / 16));
    k_repack_w<<<2304, 256, 0, stream>>>(wgt, wbTt);
    k_flag<<<1, 256, 0, stream>>>(sh1, sh2, flag);
    k_repack_x<<<32 * 49, 256, 0, stream>>>(x, sh1, sh2, xbp1, xbp2, flag);
    k_bgemm<0><<<800, 256, 0, stream>>>(xbp1, wbTt, bias, w1, flag, out);
    k_bgemm<1><<<800, 256, 0, stream>>>(xbp1, wbTt, bias, w1, flag, out);
    k_bgemm<2><<<800, 256, 0, stream>>>(xbp2, wbTt, bias, w1, flag, out);
}

// Round 6
// 146.685 us; speedup vs baseline: 2.3906x; 1.1435x over previous
//
#include <hip/hip_runtime.h>
#include <stdint.h>

typedef __attribute__((ext_vector_type(4))) int   i32x4v;
typedef __attribute__((ext_vector_type(16))) int  i32x16v;
typedef __attribute__((ext_vector_type(4))) float f32x4;

#define PIX 3136            // 56*56
#define WW 56
#define SLAB 215296         // 58*58*64 bytes, one (n,chunk64) plane
#define APLANE 5600         // LDS bytes per 16B-subchunk plane (350 units)
#define AWIN   22400        // 4 * APLANE

// workspace (bytes): two planar i8 tensors + transposed weights + flag
#define XBP_BYTES ((size_t)32*4*3364*64)          // 27,557,888
#define OFF_XBP2  (XBP_BYTES)
#define OFF_WBT   (2*XBP_BYTES)
#define WBT_BYTES ((size_t)9*16*256*16)           // 589,824
#define OFF_FLAG  (OFF_WBT + WBT_BYTES)
#define WS_NEED   (OFF_FLAG + 64)

__global__ void k_flag(const float* __restrict__ s1, const float* __restrict__ s2,
                       int* __restrict__ flag) {
    __shared__ int bad;
    int t = threadIdx.x;
    if (t == 0) bad = 0;
    __syncthreads();
    if (s1[t] != s2[t]) atomicAdd(&bad, 1);
    __syncthreads();
    if (t == 0) *flag = (bad == 0) ? 1 : 0;
}

// Zero only the 1-px halo ring of each 58x58x64 slab. 912 16B units per slab.
__global__ __launch_bounds__(256) void k_zero_halo(char* __restrict__ ws,
                                                   const int* __restrict__ flag) {
    int slab = blockIdx.x;                // 0..127 xbp1, 128..255 xbp2
    if (slab >= 128 && *flag != 0) return;
    char* base = ws + (size_t)slab * SLAB;
    int t = threadIdx.x;
    int4 z = {0, 0, 0, 0};
#pragma unroll
    for (int i = 0; i < 4; ++i) {
        int u = t + i * 256;
        if (u >= 912) break;
        int off;
        if (u < 232)      off = u;                               // top row
        else if (u < 464) off = 57 * 232 + (u - 232);            // bottom row
        else if (u < 688) { int r = (u - 464) >> 2; off = (r + 1) * 232 + ((u - 464) & 3); }
        else              { int r = (u - 688) >> 2; off = (r + 1) * 232 + 228 + ((u - 688) & 3); }
        *(int4*)(base + off * 16) = z;
    }
}

// wbTt[kk][sub16][oc256][16B]: c = sub*16 + lo
__global__ void k_repack_w(const float* __restrict__ w, char* __restrict__ wbTt) {
    int idx = blockIdx.x * 256 + threadIdx.x;     // 0..589823
    int kk = idx >> 16;
    int sub = (idx >> 12) & 15;
    int oc = (idx >> 4) & 255;
    int lo = idx & 15;
    int c = sub * 16 + lo;
    float v = w[(oc * 256 + c) * 9 + kk];
    wbTt[idx] = (v > 0.f) ? (char)1 : ((v < 0.f) ? (char)-1 : (char)0);
}

// NCHW fp32 -> planar halo-padded i8: xbp[n][plane4][py][px][64] = sign(x+shift)
__global__ __launch_bounds__(256) void k_repack_x(
    const float* __restrict__ x, const float* __restrict__ sh1,
    const float* __restrict__ sh2, char* __restrict__ xbp1,
    char* __restrict__ xbp2, const int* __restrict__ flag) {
    __shared__ float lds[64 * 68];
    bool eq = (*flag != 0);
    int t = threadIdx.x;
    int b = blockIdx.x;
    int n = b / 49;
    int p0 = (b % 49) * 64;

    int pixw = t >> 2;               // 0..63
    int sub  = t & 3;
    int pw = p0 + pixw;
    int yw = pw / WW, xw = pw % WW;

    int cl = t >> 4;
    int p4 = (t & 15) * 4;

    for (int cc = 0; cc < 256; cc += 64) {
        __syncthreads();
#pragma unroll
        for (int i = 0; i < 4; ++i) {
            float4 v = *(const float4*)(x + (size_t)(n * 256 + cc + cl + i * 16) * PIX + p0 + p4);
            *(float4*)(&lds[(cl + i * 16) * 68 + p4]) = v;
        }
        __syncthreads();
        size_t obase = (size_t)(n * 4 + (cc >> 6)) * SLAB
                     + ((size_t)(yw + 1) * 58 + (xw + 1)) * 64 + sub * 16;
        union { char c[16]; int4 v; } u1, u2;
#pragma unroll
        for (int k = 0; k < 16; ++k) {
            int c = sub * 16 + k;
            float v = lds[c * 68 + pixw];
            float a1 = v + sh1[cc + c];
            float a2 = v + sh2[cc + c];
            u1.c[k] = (a1 > 0.f) ? (char)1 : ((a1 < 0.f) ? (char)-1 : (char)0);
            u2.c[k] = (a2 > 0.f) ? (char)1 : ((a2 < 0.f) ? (char)-1 : (char)0);
        }
        *(int4*)(xbp1 + obase) = u1.v;
        if (!eq) *(int4*)(xbp2 + obase) = u2.v;
    }
}

// Implicit-GEMM binary conv, i8 MFMA. B read L2->registers (no B LDS, no per-tap
// barrier). Block: 256 thr = 4 waves (2px x 2oc). Tile 128px x 128oc. 4 barriers.
// MODE 0: EQ: out=(acc+b)*(1+w1). MODE 1: out=acc+(1+w1)b. MODE 2: out+=w1*acc.
template <int MODE>
__global__ __launch_bounds__(256, 2) void k_bgemm(
    const char* __restrict__ xsrc, const char* __restrict__ wbTt,
    const float* __restrict__ bias, const float* __restrict__ w1,
    const int* __restrict__ flag, float* __restrict__ out) {
    bool eq = (*flag != 0);
    if (MODE == 0 ? !eq : eq) return;    // block-uniform

    __shared__ char lds[AWIN];

    int t = threadIdx.x;
    int l = t & 63, wid = t >> 6;
    int wr = wid >> 1, wc = wid & 1;
    int r32 = l & 31, half = l >> 5;

    // XCD-chunked swizzle: 1600 % 8 == 0, hw XCD = blockIdx % 8 (heuristic only)
    int logical = (blockIdx.x & 7) * 200 + (blockIdx.x >> 3);
    int ntile = logical & 1;
    int m = logical >> 1;                // 0..799
    int n = m / 25, tp = m % 25;
    int p0 = tp * 128;
    int y0 = p0 / WW;
    int pyw0 = (y0 < 52) ? y0 : 52;      // window rows pyw0..pyw0+5
    int obase = ntile * 128 + wc * 64;
    int n4 = n * 4;

    // per-lane window pixel unit for the two 32-px row groups (clamped pad tail)
    int wpm[2];
#pragma unroll
    for (int mi = 0; mi < 2; ++mi) {
        int g = p0 + wr * 64 + mi * 32 + r32;
        if (g > 3135) g = 3135;          // only in fully-discarded waves
        int y = g / WW, xx = g - y * WW;
        wpm[mi] = (y + 1 - pyw0) * 58 + xx + 1;
    }

    int4 rA[6];
    i32x4v bf[2][2][2];                  // [parity][kq][ni]

    auto loadRA = [&](int cc_) {
        const char* sb = xsrc + (size_t)(n4 + cc_) * SLAB + (size_t)pyw0 * 3712;
#pragma unroll
        for (int j = 0; j < 6; ++j) {
            int u = t + j * 256;
            if (u < 1392) rA[j] = *(const int4*)(sb + u * 16);
        }
    };
    auto writeA = [&]() {
#pragma unroll
        for (int j = 0; j < 6; ++j) {
            int u = t + j * 256;
            if (u < 1392) *(int4*)(lds + (u & 3) * APLANE + (u >> 2) * 16) = rA[j];
        }
    };
    auto loadB = [&](int par, int cc_, int kk_) {
#pragma unroll
        for (int kq = 0; kq < 2; ++kq)
#pragma unroll
            for (int ni = 0; ni < 2; ++ni)
                bf[par][kq][ni] = *(const i32x4v*)(wbTt +
                    (((size_t)((kk_ * 16 + cc_ * 4 + kq * 2 + half) * 256
                               + obase + ni * 32 + r32)) << 4));
    };

    i32x16v acc[2][2];
#pragma unroll
    for (int mi = 0; mi < 2; ++mi)
#pragma unroll
        for (int ni = 0; ni < 2; ++ni)
#pragma unroll
            for (int i = 0; i < 16; ++i) acc[mi][ni][i] = 0;

    // prologue: A(0) and B(s=0)
    loadRA(0);
    loadB(0, 0, 0);

#pragma unroll
    for (int cc = 0; cc < 4; ++cc) {
        __syncthreads();                 // all waves done reading old window
        writeA();                        // waits rA (vmcnt-counted)
        __syncthreads();                 // window ready
#pragma unroll
        for (int kk = 0; kk < 9; ++kk) {
            const int s = cc * 9 + kk;
            const int cur = s & 1, nxt = cur ^ 1;
            if (kk < 8)       loadB(nxt, cc, kk + 1);
            else if (cc < 3)  loadB(nxt, cc + 1, 0);
            if (kk == 7 && cc < 3) loadRA(cc + 1);
            const int ts = (kk / 3 - 1) * 58 + (kk % 3) - 1;
#pragma unroll
            for (int kq = 0; kq < 2; ++kq) {
                int ci = kq * 2 + half;
                i32x4v af0 = *(const i32x4v*)(lds + ci * APLANE + (wpm[0] + ts) * 16);
                i32x4v af1 = *(const i32x4v*)(lds + ci * APLANE + (wpm[1] + ts) * 16);
                acc[0][0] = __builtin_amdgcn_mfma_i32_32x32x32_i8(af0, bf[cur][kq][0], acc[0][0], 0, 0, 0);
                acc[0][1] = __builtin_amdgcn_mfma_i32_32x32x32_i8(af0, bf[cur][kq][1], acc[0][1], 0, 0, 0);
                acc[1][0] = __builtin_amdgcn_mfma_i32_32x32x32_i8(af1, bf[cur][kq][0], acc[1][0], 0, 0, 0);
                acc[1][1] = __builtin_amdgcn_mfma_i32_32x32x32_i8(af1, bf[cur][kq][1], acc[1][1], 0, 0, 0);
            }
        }
    }

    // ---- epilogue: per-wave LDS transpose -> coalesced stores ----
    __syncthreads();                     // A window dead; reuse as 4x5600B wave-private
    float w1v = w1[0];
    float se = 1.f + w1v;
    char* ep = lds + wid * APLANE;       // [32 oc][33 px] f32 = 4224B

#pragma unroll
    for (int mi = 0; mi < 2; ++mi) {
        int pfrag = p0 + wr * 64 + mi * 32;
        bool pvalid = pfrag < PIX;
#pragma unroll
        for (int ni = 0; ni < 2; ++ni) {
            float bv = bias[obase + ni * 32 + r32];
#pragma unroll
            for (int q = 0; q < 4; ++q) {
                f32x4 v;
#pragma unroll
                for (int j = 0; j < 4; ++j) {
                    float a = (float)(acc[mi][ni][q * 4 + j]);
                    if (MODE == 0)      v[j] = (a + bv) * se;
                    else if (MODE == 1) v[j] = a + se * bv;
                    else                v[j] = w1v * a;
                }
                *(f32x4*)(ep + ((r32 * 33 + q * 8 + half * 4) << 2)) = v;
            }
            if (pvalid) {
#pragma unroll
                for (int step = 0; step < 4; ++step) {
                    int or4 = step * 8 + (l >> 3);
                    int pq = l & 7;
                    f32x4 v = *(const f32x4*)(ep + ((or4 * 33 + pq * 4) << 2));
                    float* op = out + ((size_t)(n * 256 + obase + ni * 32 + or4)) * PIX
                              + pfrag + pq * 4;
                    if (MODE == 2) {
                        f32x4 o = *(const f32x4*)op;
                        v[0] += o[0]; v[1] += o[1]; v[2] += o[2]; v[3] += o[3];
                    }
                    *(f32x4*)op = v;
                }
            }
        }
    }
}

extern "C" void kernel_launch(void* const* d_in, const int* in_sizes, int n_in,
                              void* d_out, int out_size, void* d_ws, size_t ws_size,
                              hipStream_t stream) {
    const float* x    = (const float*)d_in[0];
    const float* sh1  = (const float*)d_in[1];
    const float* sh2  = (const float*)d_in[2];
    const float* wgt  = (const float*)d_in[3];
    const float* bias = (const float*)d_in[4];
    const float* w1   = (const float*)d_in[5];
    float* out = (float*)d_out;
    char* ws = (char*)d_ws;
    if (ws_size < WS_NEED) return;

    char* xbp1 = ws;
    char* xbp2 = ws + OFF_XBP2;
    char* wbTt = ws + OFF_WBT;
    int* flag  = (int*)(ws + OFF_FLAG);

    k_flag<<<1, 256, 0, stream>>>(sh1, sh2, flag);
    k_zero_halo<<<256, 256, 0, stream>>>(ws, flag);
    k_repack_w<<<2304, 256, 0, stream>>>(wgt, wbTt);
    k_repack_x<<<32 * 49, 256, 0, stream>>>(x, sh1, sh2, xbp1, xbp2, flag);
    k_bgemm<0><<<1600, 256, 0, stream>>>(xbp1, wbTt, bias, w1, flag, out);
    k_bgemm<1><<<1600, 256, 0, stream>>>(xbp1, wbTt, bias, w1, flag, out);
    k_bgemm<2><<<1600, 256, 0, stream>>>(xbp2, wbTt, bias, w1, flag, out);
}